// Round 4
// baseline (297.717 us; speedup 1.0000x reference)
//
#include <hip/hip_runtime.h>
#include <hip/hip_bf16.h>

#define N_NODES 50000
#define N_EDGES 800000
#define N_RELS  8
#define FEATS   128
#define NB_SCAN 196   // ceil(50000/256)

typedef __attribute__((ext_vector_type(8))) short bf16x8;
typedef __attribute__((ext_vector_type(4))) float f32x4;

__device__ __forceinline__ unsigned short f2b(float f) {
    unsigned int u = __float_as_uint(f);
    u += 0x7fffu + ((u >> 16) & 1u);
    return (unsigned short)(u >> 16);
}

// ---- convert h (fp32 -> bf16), 4 elems/thread ----
__global__ void cvt_h_kernel(const float* __restrict__ h, unsigned short* __restrict__ hb) {
    int i = blockIdx.x * 256 + threadIdx.x;
    float4 v = ((const float4*)h)[i];
    ushort4 o;
    o.x = f2b(v.x); o.y = f2b(v.y); o.z = f2b(v.z); o.w = f2b(v.w);
    ((ushort4*)hb)[i] = o;
}

// ---- convert + transpose W: w[r][k][o] -> wt[r][o][k] bf16 ----
__global__ void cvt_w_kernel(const float* __restrict__ w, unsigned short* __restrict__ wt) {
    int idx = blockIdx.x * 256 + threadIdx.x;        // 131072
    int r = idx >> 14;
    int k = (idx >> 7) & 127;
    int o = idx & 127;
    wt[(r << 14) + o * 128 + k] = f2b(w[idx]);
}

// ---- batched GEMM: ht[n][r][o] = sum_k h[n][k] * w[r][k][o], bf16 MFMA ----
// tile: 128 nodes x 128 o, K=128. A-operand = wt rows (o major), B-operand = hb rows
// => D[m=o][n=node]: lane gets 4 consecutive o per acc reg -> 8B packed stores.
__global__ __launch_bounds__(256) void gemm_kernel(const unsigned short* __restrict__ hb,
                                                   const unsigned short* __restrict__ wt,
                                                   unsigned short* __restrict__ ht) {
    __shared__ unsigned short Ws[128 * 136];   // wt[r] tile, [o][k], +8 pad
    __shared__ unsigned short Hs[128 * 136];   // h tile,  [node][k]
    const int r  = blockIdx.y;
    const int n0 = blockIdx.x * 128;
    const int tid = threadIdx.x;

    const unsigned short* wtr = wt + ((size_t)r << 14);
    #pragma unroll
    for (int i = 0; i < 8; ++i) {
        int idx = tid + i * 256;                 // 0..2047, 16 chunks/row
        int row = idx >> 4, ck = idx & 15;
        uint4 v = *(const uint4*)&wtr[row * 128 + ck * 8];
        *(uint4*)&Ws[row * 136 + ck * 8] = v;
        int n = n0 + row;
        uint4 hv = make_uint4(0u, 0u, 0u, 0u);
        if (n < N_NODES) hv = *(const uint4*)&hb[(size_t)n * 128 + ck * 8];
        *(uint4*)&Hs[row * 136 + ck * 8] = hv;
    }
    __syncthreads();

    const int wave = tid >> 6;    // wave handles nodes [wave*32, wave*32+32), all 128 o
    const int lane = tid & 63;
    const int m16  = lane & 15;
    const int quad = lane >> 4;

    f32x4 acc[8][2];
    #pragma unroll
    for (int ot = 0; ot < 8; ++ot)
        #pragma unroll
        for (int nt = 0; nt < 2; ++nt) acc[ot][nt] = (f32x4){0.f, 0.f, 0.f, 0.f};

    #pragma unroll
    for (int kk = 0; kk < 4; ++kk) {
        bf16x8 b[2];
        #pragma unroll
        for (int nt = 0; nt < 2; ++nt)
            b[nt] = *(const bf16x8*)&Hs[(wave * 32 + nt * 16 + m16) * 136 + kk * 32 + quad * 8];
        #pragma unroll
        for (int ot = 0; ot < 8; ++ot) {
            bf16x8 a = *(const bf16x8*)&Ws[(ot * 16 + m16) * 136 + kk * 32 + quad * 8];
            #pragma unroll
            for (int nt = 0; nt < 2; ++nt)
                acc[ot][nt] = __builtin_amdgcn_mfma_f32_16x16x32_bf16(a, b[nt], acc[ot][nt], 0, 0, 0);
        }
    }

    // C/D: col=lane&15 = node-within-tile, row=quad*4+reg = o-within-tile
    #pragma unroll
    for (int nt = 0; nt < 2; ++nt) {
        int n = n0 + wave * 32 + nt * 16 + m16;
        if (n >= N_NODES) continue;
        unsigned short* dstp = &ht[(size_t)n * (N_RELS * 128) + r * 128 + quad * 4];
        #pragma unroll
        for (int ot = 0; ot < 8; ++ot) {
            ushort4 o4;
            o4.x = f2b(acc[ot][nt][0]);
            o4.y = f2b(acc[ot][nt][1]);
            o4.z = f2b(acc[ot][nt][2]);
            o4.w = f2b(acc[ot][nt][3]);
            *(ushort4*)(dstp + ot * 16) = o4;
        }
    }
}

// ---- histogram of dst ----
__global__ void hist_kernel(const int* __restrict__ dst, int* __restrict__ counts) {
    int e = blockIdx.x * 256 + threadIdx.x;
    atomicAdd(&counts[dst[e]], 1);
}

// ---- scan phase 1: per-block exclusive scan + block sums ----
__global__ void scan1_kernel(const int* __restrict__ counts, int* __restrict__ partial,
                             int* __restrict__ bsum) {
    __shared__ int tmp[256];
    int i = blockIdx.x * 256 + threadIdx.x;
    int v = (i < N_NODES) ? counts[i] : 0;
    tmp[threadIdx.x] = v;
    __syncthreads();
    #pragma unroll
    for (int off = 1; off < 256; off <<= 1) {
        int t = (threadIdx.x >= off) ? tmp[threadIdx.x - off] : 0;
        __syncthreads();
        tmp[threadIdx.x] += t;
        __syncthreads();
    }
    if (i < N_NODES) partial[i] = tmp[threadIdx.x] - v;   // exclusive
    if (threadIdx.x == 255) bsum[blockIdx.x] = tmp[255];
}

// ---- scan phase 2: exclusive scan of block sums (single block) ----
__global__ void scan2_kernel(int* __restrict__ bsum) {
    __shared__ int tmp[256];
    int i = threadIdx.x;
    int v = (i < NB_SCAN) ? bsum[i] : 0;
    tmp[i] = v;
    __syncthreads();
    #pragma unroll
    for (int off = 1; off < 256; off <<= 1) {
        int t = (i >= off) ? tmp[i - off] : 0;
        __syncthreads();
        tmp[i] += t;
        __syncthreads();
    }
    if (i < NB_SCAN) bsum[i] = tmp[i] - v;
}

// ---- scan phase 3: add block offsets; init row_start + cursor ----
__global__ void scan3_kernel(const int* __restrict__ partial, const int* __restrict__ bsum,
                             int* __restrict__ row_start, int* __restrict__ cursor) {
    int i = blockIdx.x * 256 + threadIdx.x;
    if (i < N_NODES) {
        int rs = partial[i] + bsum[i >> 8];
        row_start[i] = rs;
        cursor[i] = rs;
    }
    if (i == 0) row_start[N_NODES] = N_EDGES;
}

// ---- scatter edges into dst-sorted order; meta.x = precomputed ht byte offset ----
__global__ void scatter_kernel(const int* __restrict__ src, const int* __restrict__ dst,
                               const int* __restrict__ et, const float* __restrict__ en,
                               int* __restrict__ cursor, int2* __restrict__ meta) {
    int e = blockIdx.x * 256 + threadIdx.x;
    int d = dst[e];
    int pos = atomicAdd(&cursor[d], 1);
    meta[pos] = make_int2((src[e] << 11) + (et[e] << 8), __float_as_int(en[e]));
}

// ---- gather: one wave per dst node, fused bias+relu ----
__global__ __launch_bounds__(256) void gather_kernel(const char* __restrict__ ht,
                                                     const int2* __restrict__ meta,
                                                     const int* __restrict__ row_start,
                                                     const float* __restrict__ bias,
                                                     float* __restrict__ out) {
    int node = blockIdx.x * 4 + (threadIdx.x >> 6);   // grid 12500 * 4 waves = 50000
    int lane = threadIdx.x & 63;
    int laneoff = lane * 4;
    int beg = row_start[node], end = row_start[node + 1];
    float a0 = 0.f, a1 = 0.f;
    for (int base = beg; base < end; base += 64) {
        int cnt = end - base; if (cnt > 64) cnt = 64;
        int2 m = make_int2(0, 0);
        if (base + lane < end) m = meta[base + lane];
        #pragma unroll 4
        for (int k = 0; k < cnt; ++k) {
            int off = __shfl(m.x, k);
            float w = __uint_as_float(__shfl(m.y, k));
            unsigned int v = *(const unsigned int*)(ht + off + laneoff);
            a0 += __uint_as_float(v << 16) * w;
            a1 += __uint_as_float(v & 0xffff0000u) * w;
        }
    }
    float2 b = *(const float2*)&bias[lane * 2];
    float2 o = make_float2(fmaxf(a0 + b.x, 0.f), fmaxf(a1 + b.y, 0.f));
    *(float2*)&out[((size_t)node << 7) + lane * 2] = o;
}

extern "C" void kernel_launch(void* const* d_in, const int* in_sizes, int n_in,
                              void* d_out, int out_size, void* d_ws, size_t ws_size,
                              hipStream_t stream) {
    const float* h    = (const float*)d_in[0];
    const float* en   = (const float*)d_in[1];
    const int*   et   = (const int*)d_in[2];
    const int*   src  = (const int*)d_in[3];
    const int*   dst  = (const int*)d_in[4];
    const float* w    = (const float*)d_in[5];
    const float* bias = (const float*)d_in[6];
    float* out = (float*)d_out;

    char* ws = (char*)d_ws;
    unsigned short* hb  = (unsigned short*)(ws);                 // 12,800,000 B
    unsigned short* wt  = (unsigned short*)(ws + 12800000);      //    262,144 B
    unsigned short* ht  = (unsigned short*)(ws + 13062144);      // 102,400,000 B
    char* sbase = ws + 115462144;
    int*  counts    = (int*)(sbase);                             // 200,704 B slot
    int*  partial   = (int*)(sbase + 200704);
    int*  bsum      = (int*)(sbase + 401408);                    //   1,024 B slot
    int*  row_start = (int*)(sbase + 402432);                    // 50001 ints
    int*  cursor    = (int*)(sbase + 603136);
    int2* meta      = (int2*)(sbase + 803840);                   // 6,400,000 B

    (void)hipMemsetAsync(counts, 0, N_NODES * sizeof(int), stream);
    hipLaunchKernelGGL(cvt_h_kernel, dim3(6250), dim3(256), 0, stream, h, hb);
    hipLaunchKernelGGL(cvt_w_kernel, dim3(512), dim3(256), 0, stream, w, wt);
    hipLaunchKernelGGL(gemm_kernel, dim3(391, N_RELS), dim3(256), 0, stream, hb, wt, ht);
    hipLaunchKernelGGL(hist_kernel, dim3(N_EDGES / 256), dim3(256), 0, stream, dst, counts);
    hipLaunchKernelGGL(scan1_kernel, dim3(NB_SCAN), dim3(256), 0, stream, counts, partial, bsum);
    hipLaunchKernelGGL(scan2_kernel, dim3(1), dim3(256), 0, stream, bsum);
    hipLaunchKernelGGL(scan3_kernel, dim3(NB_SCAN), dim3(256), 0, stream, partial, bsum, row_start, cursor);
    hipLaunchKernelGGL(scatter_kernel, dim3(N_EDGES / 256), dim3(256), 0, stream, src, dst, et, en, cursor, meta);
    hipLaunchKernelGGL(gather_kernel, dim3(12500), dim3(256), 0, stream, (const char*)ht, meta, row_start, bias, out);
}

// Round 5
// 286.704 us; speedup vs baseline: 1.0384x; 1.0384x over previous
//
#include <hip/hip_runtime.h>
#include <hip/hip_bf16.h>

#define N_NODES 50000
#define PADN    50048   // 391 * 128
#define N_EDGES 800000
#define N_RELS  8
#define NB_SCAN 196     // ceil(50000/256)

typedef __attribute__((ext_vector_type(8))) short bf16x8;
typedef __attribute__((ext_vector_type(4))) float f32x4;

__device__ __forceinline__ unsigned short f2b(float f) {
    unsigned int u = __float_as_uint(f);
    u += 0x7fffu + ((u >> 16) & 1u);
    return (unsigned short)(u >> 16);
}

// ---- convert + transpose W: w[r][k][o] -> wt[r][o][k] bf16 ----
__global__ void cvt_w_kernel(const float* __restrict__ w, unsigned short* __restrict__ wt) {
    int idx = blockIdx.x * 256 + threadIdx.x;        // 131072
    int r = idx >> 14;
    int k = (idx >> 7) & 127;
    int o = idx & 127;
    wt[(r << 14) + o * 128 + k] = f2b(w[idx]);
}

// ---- histogram of dst ----
__global__ void hist_kernel(const int* __restrict__ dst, int* __restrict__ counts) {
    int e = blockIdx.x * 256 + threadIdx.x;
    atomicAdd(&counts[dst[e]], 1);
}

// ---- scan phase 1 ----
__global__ void scan1_kernel(const int* __restrict__ counts, int* __restrict__ partial,
                             int* __restrict__ bsum) {
    __shared__ int tmp[256];
    int i = blockIdx.x * 256 + threadIdx.x;
    int v = (i < N_NODES) ? counts[i] : 0;
    tmp[threadIdx.x] = v;
    __syncthreads();
    #pragma unroll
    for (int off = 1; off < 256; off <<= 1) {
        int t = (threadIdx.x >= off) ? tmp[threadIdx.x - off] : 0;
        __syncthreads();
        tmp[threadIdx.x] += t;
        __syncthreads();
    }
    if (i < N_NODES) partial[i] = tmp[threadIdx.x] - v;
    if (threadIdx.x == 255) bsum[blockIdx.x] = tmp[255];
}

// ---- scan phase 2 ----
__global__ void scan2_kernel(int* __restrict__ bsum) {
    __shared__ int tmp[256];
    int i = threadIdx.x;
    int v = (i < NB_SCAN) ? bsum[i] : 0;
    tmp[i] = v;
    __syncthreads();
    #pragma unroll
    for (int off = 1; off < 256; off <<= 1) {
        int t = (i >= off) ? tmp[i - off] : 0;
        __syncthreads();
        tmp[i] += t;
        __syncthreads();
    }
    if (i < NB_SCAN) bsum[i] = tmp[i] - v;
}

// ---- scan phase 3 ----
__global__ void scan3_kernel(const int* __restrict__ partial, const int* __restrict__ bsum,
                             int* __restrict__ row_start, int* __restrict__ cursor) {
    int i = blockIdx.x * 256 + threadIdx.x;
    if (i < N_NODES) {
        int rs = partial[i] + bsum[i >> 8];
        row_start[i] = rs;
        cursor[i] = rs;
    }
    if (i == 0) row_start[N_NODES] = N_EDGES;
}

// ---- scatter: meta.x = (src << 9) | et  (h fp32 row byte offset | rel) ----
__global__ void scatter_kernel(const int* __restrict__ src, const int* __restrict__ dst,
                               const int* __restrict__ et, const float* __restrict__ en,
                               int* __restrict__ cursor, int2* __restrict__ meta) {
    int e = blockIdx.x * 256 + threadIdx.x;
    int d = dst[e];
    int pos = atomicAdd(&cursor[d], 1);
    meta[pos] = make_int2((src[e] << 9) | et[e], __float_as_int(en[e]));
}

// ---- aggregate: one wave per dst node; per-rel fp32 accumulate of norm*h[src];
//      writes agg[r][node][128] bf16 (rel-major planes, PADN rows each) ----
__global__ __launch_bounds__(256) void agg_kernel(const char* __restrict__ h,
                                                  const int2* __restrict__ meta,
                                                  const int* __restrict__ row_start,
                                                  unsigned short* __restrict__ agg) {
    int node = blockIdx.x * 4 + (threadIdx.x >> 6);   // 12500 * 4 = 50000
    int lane = threadIdx.x & 63;
    int beg = row_start[node], end = row_start[node + 1];
    float2 acc[N_RELS];
    #pragma unroll
    for (int r = 0; r < N_RELS; ++r) acc[r] = make_float2(0.f, 0.f);

    for (int base = beg; base < end; base += 64) {
        int cnt = end - base; if (cnt > 64) cnt = 64;
        int2 m = make_int2(0, 0);
        if (base + lane < end) m = meta[base + lane];
        #pragma unroll 2
        for (int k = 0; k < cnt; ++k) {
            int off = __shfl(m.x, k);
            float w = __uint_as_float(__shfl(m.y, k));
            float2 hv = *(const float2*)(h + (off & 0xFFFFFE00) + lane * 8);
            int r = __builtin_amdgcn_readfirstlane(off) & 7;
            float vx = hv.x * w, vy = hv.y * w;
            switch (r) {
                case 0: acc[0].x += vx; acc[0].y += vy; break;
                case 1: acc[1].x += vx; acc[1].y += vy; break;
                case 2: acc[2].x += vx; acc[2].y += vy; break;
                case 3: acc[3].x += vx; acc[3].y += vy; break;
                case 4: acc[4].x += vx; acc[4].y += vy; break;
                case 5: acc[5].x += vx; acc[5].y += vy; break;
                case 6: acc[6].x += vx; acc[6].y += vy; break;
                case 7: acc[7].x += vx; acc[7].y += vy; break;
            }
        }
    }
    #pragma unroll
    for (int r = 0; r < N_RELS; ++r) {
        unsigned int u = (unsigned int)f2b(acc[r].x) | ((unsigned int)f2b(acc[r].y) << 16);
        *(unsigned int*)&agg[((size_t)(r * PADN + node)) * 128 + lane * 2] = u;
    }
}

// ---- gemm2: out[n][o] = relu(sum_{r,k} agg[r][n][k] * wt[r][o][k] + bias[o])
//      tile 128 nodes x 128 o, K = 8 rels x 128; wave = (wo, wn) quadrant, 4x4 acc ----
__global__ __launch_bounds__(256) void gemm2_kernel(const unsigned short* __restrict__ agg,
                                                    const unsigned short* __restrict__ wt,
                                                    const float* __restrict__ bias,
                                                    float* __restrict__ out) {
    __shared__ unsigned short Ws[128 * 136];   // wt[r] [o][k], +8 pad
    __shared__ unsigned short Bs[128 * 136];   // agg chunk [node][k]
    const int n0 = blockIdx.x * 128;
    const int tid = threadIdx.x;
    const int wave = tid >> 6;
    const int lane = tid & 63;
    const int m16  = lane & 15;
    const int quad = lane >> 4;
    const int wo = wave & 1;     // o half (64)
    const int wn = wave >> 1;    // node half (64)

    f32x4 acc[4][4];
    #pragma unroll
    for (int og = 0; og < 4; ++og)
        #pragma unroll
        for (int ng = 0; ng < 4; ++ng) acc[og][ng] = (f32x4){0.f, 0.f, 0.f, 0.f};

    for (int r = 0; r < N_RELS; ++r) {
        const unsigned short* wtr = wt + ((size_t)r << 14);
        const unsigned short* agr = agg + ((size_t)(r * PADN + n0)) * 128;
        #pragma unroll
        for (int i = 0; i < 8; ++i) {
            int idx = tid + i * 256;             // 0..2047
            int row = idx >> 4, ck = idx & 15;
            *(uint4*)&Ws[row * 136 + ck * 8] = *(const uint4*)&wtr[row * 128 + ck * 8];
            *(uint4*)&Bs[row * 136 + ck * 8] = *(const uint4*)&agr[row * 128 + ck * 8];
        }
        __syncthreads();
        #pragma unroll
        for (int kk = 0; kk < 4; ++kk) {
            bf16x8 a[4], b[4];
            #pragma unroll
            for (int i = 0; i < 4; ++i) {
                a[i] = *(const bf16x8*)&Ws[(wo * 64 + i * 16 + m16) * 136 + kk * 32 + quad * 8];
                b[i] = *(const bf16x8*)&Bs[(wn * 64 + i * 16 + m16) * 136 + kk * 32 + quad * 8];
            }
            #pragma unroll
            for (int og = 0; og < 4; ++og)
                #pragma unroll
                for (int ng = 0; ng < 4; ++ng)
                    acc[og][ng] = __builtin_amdgcn_mfma_f32_16x16x32_bf16(a[og], b[ng], acc[og][ng], 0, 0, 0);
        }
        __syncthreads();
    }

    // C/D: col(m16)=node, row(quad*4+reg)=o
    #pragma unroll
    for (int og = 0; og < 4; ++og) {
        int ob = wo * 64 + og * 16 + quad * 4;
        float4 b4 = *(const float4*)&bias[ob];
        #pragma unroll
        for (int ng = 0; ng < 4; ++ng) {
            int n = n0 + wn * 64 + ng * 16 + m16;
            if (n < N_NODES) {
                float4 v;
                v.x = fmaxf(acc[og][ng][0] + b4.x, 0.f);
                v.y = fmaxf(acc[og][ng][1] + b4.y, 0.f);
                v.z = fmaxf(acc[og][ng][2] + b4.z, 0.f);
                v.w = fmaxf(acc[og][ng][3] + b4.w, 0.f);
                *(float4*)&out[(size_t)n * 128 + ob] = v;
            }
        }
    }
}

extern "C" void kernel_launch(void* const* d_in, const int* in_sizes, int n_in,
                              void* d_out, int out_size, void* d_ws, size_t ws_size,
                              hipStream_t stream) {
    const float* h    = (const float*)d_in[0];
    const float* en   = (const float*)d_in[1];
    const int*   et   = (const int*)d_in[2];
    const int*   src  = (const int*)d_in[3];
    const int*   dst  = (const int*)d_in[4];
    const float* w    = (const float*)d_in[5];
    const float* bias = (const float*)d_in[6];
    float* out = (float*)d_out;

    char* ws = (char*)d_ws;
    unsigned short* wt  = (unsigned short*)(ws);                 //     262,144 B
    unsigned short* agg = (unsigned short*)(ws + 262144);        // 102,498,304 B (8 * PADN * 256)
    char* sbase = ws + 102760448;
    int*  counts    = (int*)(sbase);
    int*  partial   = (int*)(sbase + 200704);
    int*  bsum      = (int*)(sbase + 401408);
    int*  row_start = (int*)(sbase + 402432);                    // 50001 ints
    int*  cursor    = (int*)(sbase + 603136);
    int2* meta      = (int2*)(sbase + 803840);                   // 6,400,000 B

    (void)hipMemsetAsync(counts, 0, N_NODES * sizeof(int), stream);
    hipLaunchKernelGGL(cvt_w_kernel, dim3(512), dim3(256), 0, stream, w, wt);
    hipLaunchKernelGGL(hist_kernel, dim3(N_EDGES / 256), dim3(256), 0, stream, dst, counts);
    hipLaunchKernelGGL(scan1_kernel, dim3(NB_SCAN), dim3(256), 0, stream, counts, partial, bsum);
    hipLaunchKernelGGL(scan2_kernel, dim3(1), dim3(256), 0, stream, bsum);
    hipLaunchKernelGGL(scan3_kernel, dim3(NB_SCAN), dim3(256), 0, stream, partial, bsum, row_start, cursor);
    hipLaunchKernelGGL(scatter_kernel, dim3(N_EDGES / 256), dim3(256), 0, stream, src, dst, et, en, cursor, meta);
    hipLaunchKernelGGL(agg_kernel, dim3(12500), dim3(256), 0, stream, (const char*)h, meta, row_start, agg);
    hipLaunchKernelGGL(gemm2_kernel, dim3(391), dim3(256), 0, stream, agg, wt, bias, out);
}